// Round 1
// baseline (183.970 us; speedup 1.0000x reference)
//
#include <hip/hip_runtime.h>

#define DEVI __device__ __forceinline__

typedef float fv4 __attribute__((ext_vector_type(4)));
typedef __bf16 bf16x8 __attribute__((ext_vector_type(8)));
typedef unsigned short u16x8 __attribute__((ext_vector_type(8)));
typedef unsigned short u16x4 __attribute__((ext_vector_type(4)));

DEVI unsigned short f2bf(float f) {
  unsigned int u = __builtin_bit_cast(unsigned int, f);
  return (unsigned short)((u + 0x7fffu + ((u >> 16) & 1u)) >> 16);
}
DEVI fv4 ldv4(const float* p) { return *reinterpret_cast<const fv4*>(p); }
DEVI u16x8 pk8(fv4 a, fv4 b) {
  u16x8 u;
  u[0] = f2bf(a[0]); u[1] = f2bf(a[1]); u[2] = f2bf(a[2]); u[3] = f2bf(a[3]);
  u[4] = f2bf(b[0]); u[5] = f2bf(b[1]); u[6] = f2bf(b[2]); u[7] = f2bf(b[3]);
  return u;
}
DEVI bf16x8 asbf(u16x8 u) { return __builtin_bit_cast(bf16x8, u); }
DEVI fv4 MFMA16(bf16x8 a, bf16x8 b, fv4 c) {
  return __builtin_amdgcn_mfma_f32_16x16x32_bf16(a, b, c, 0, 0, 0);
}
DEVI float siluf(float x) { return x / (1.f + __expf(-x)); }

// ---------------- adaLN modulation: ada[b][r] = dot(silu(t_emb[b]), W_ada[r]) + b_ada[r]
__global__ __launch_bounds__(256)
void k_ada(const float* __restrict__ temb, const float* __restrict__ W_ada,
           const float* __restrict__ b_ada, float* __restrict__ ada) {
  __shared__ float sm[256];
  const int b = blockIdx.x / 6;
  const int r = (blockIdx.x % 6) * 256 + threadIdx.x;
  float te = temb[b * 256 + threadIdx.x];
  sm[threadIdx.x] = siluf(te);
  __syncthreads();
  float s = b_ada[r];
  const float* wr = W_ada + (size_t)r * 256;
  for (int k = 0; k < 256; ++k) s += sm[k] * wr[k];
  ada[b * 1536 + r] = s;
}

// ---------------- LN(x*mask) then modulate with ada[shift_off/scale_off]
__global__ __launch_bounds__(256)
void k_xnorm(const float* __restrict__ xin, const float* __restrict__ mask,
             const float* __restrict__ ada, int shift_off, int scale_off,
             float* __restrict__ out) {
  const int row = blockIdx.x;     // 0..767  (b*384+n)
  const int b = row / 384;
  const int t = threadIdx.x;
  const float m = mask[row];
  const float v = xin[(size_t)row * 256 + t] * m;
  float s = v, ss = v * v;
#pragma unroll
  for (int o = 1; o < 64; o <<= 1) { s += __shfl_xor(s, o); ss += __shfl_xor(ss, o); }
  __shared__ float red[8];
  const int wid = t >> 6;
  if ((t & 63) == 0) { red[wid] = s; red[4 + wid] = ss; }
  __syncthreads();
  s = red[0] + red[1] + red[2] + red[3];
  ss = red[4] + red[5] + red[6] + red[7];
  const float mean = s * (1.f / 256.f);
  const float var = ss * (1.f / 256.f) - mean * mean;
  const float rs = rsqrtf(var + 1e-6f);
  const float sc = ada[b * 1536 + scale_off + t];
  const float sh = ada[b * 1536 + shift_off + t];
  out[(size_t)row * 256 + t] = (v - mean) * rs * (1.f + sc) + sh;
}

// ---------------- generic bf16 MFMA GEMM: C[M x N] = A[M x K] * Brow(c)^T
// Brow(c) = B + c*ldb + koff.  64x64 tile/block, 4 waves (2x2 of 32x32).
// EPI: 0 none; 1 +bscale*bias[col]; 2 res+gate*acc; 3 (res+gate*acc)*mask; 4 transposed store
template <int EPI>
__global__ __launch_bounds__(256)
void k_gemm(const float* __restrict__ A, int lda,
            const float* __restrict__ B, int ldb, int koff, int K,
            float* __restrict__ C, int ldc,
            const float* __restrict__ bias, float bscale,
            const float* __restrict__ res,
            const float* __restrict__ ada, int gate_off,
            const float* __restrict__ mask) {
  __shared__ __align__(16) unsigned short As[64 * 64];
  __shared__ __align__(16) unsigned short Bs[64 * 64];
  const int t = threadIdx.x, lane = t & 63, w = t >> 6;
  const int bn0 = blockIdx.x * 64, bm0 = blockIdx.y * 64;
  const int qr = (w >> 1) * 32, qc = (w & 1) * 32;
  const int g = lane >> 4, c = lane & 15;
  const int srow = t >> 2;         // 0..63
  const int so = (t & 3) * 2;      // octet 0,2,4,6
  const int o0 = so ^ (srow & 7), o1 = (so + 1) ^ (srow & 7);
  unsigned short* aw0 = As + srow * 64 + o0 * 8;
  unsigned short* aw1 = As + srow * 64 + o1 * 8;
  unsigned short* bw0 = Bs + srow * 64 + o0 * 8;
  unsigned short* bw1 = Bs + srow * 64 + o1 * 8;
  const float* ag = A + (size_t)(bm0 + srow) * lda + so * 8;
  const float* bg = B + (size_t)(bn0 + srow) * ldb + koff + so * 8;
  fv4 a0 = ldv4(ag), a1 = ldv4(ag + 4), a2 = ldv4(ag + 8), a3 = ldv4(ag + 12);
  fv4 c0 = ldv4(bg), c1 = ldv4(bg + 4), c2 = ldv4(bg + 8), c3 = ldv4(bg + 12);
  fv4 acc[2][2] = {};
  for (int k0 = 0; k0 < K; k0 += 64) {
    __syncthreads();
    *reinterpret_cast<u16x8*>(aw0) = pk8(a0, a1);
    *reinterpret_cast<u16x8*>(aw1) = pk8(a2, a3);
    *reinterpret_cast<u16x8*>(bw0) = pk8(c0, c1);
    *reinterpret_cast<u16x8*>(bw1) = pk8(c2, c3);
    __syncthreads();
    if (k0 + 64 < K) {  // prefetch next chunk (overlaps MFMA below)
      ag += 64; bg += 64;
      a0 = ldv4(ag); a1 = ldv4(ag + 4); a2 = ldv4(ag + 8); a3 = ldv4(ag + 12);
      c0 = ldv4(bg); c1 = ldv4(bg + 4); c2 = ldv4(bg + 8); c3 = ldv4(bg + 12);
    }
#pragma unroll
    for (int kk = 0; kk < 2; ++kk) {
      bf16x8 af[2], bf[2];
#pragma unroll
      for (int mi = 0; mi < 2; ++mi) {
        int row = qr + mi * 16 + c;
        int oct = (kk * 4 + g) ^ (row & 7);
        af[mi] = asbf(*reinterpret_cast<const u16x8*>(As + row * 64 + oct * 8));
      }
#pragma unroll
      for (int ni = 0; ni < 2; ++ni) {
        int row = qc + ni * 16 + c;
        int oct = (kk * 4 + g) ^ (row & 7);
        bf[ni] = asbf(*reinterpret_cast<const u16x8*>(Bs + row * 64 + oct * 8));
      }
#pragma unroll
      for (int mi = 0; mi < 2; ++mi)
#pragma unroll
        for (int ni = 0; ni < 2; ++ni)
          acc[mi][ni] = MFMA16(af[mi], bf[ni], acc[mi][ni]);
    }
  }
#pragma unroll
  for (int mi = 0; mi < 2; ++mi)
#pragma unroll
    for (int ni = 0; ni < 2; ++ni)
#pragma unroll
      for (int r = 0; r < 4; ++r) {
        int row = bm0 + qr + mi * 16 + g * 4 + r;
        int col = bn0 + qc + ni * 16 + c;
        float v = acc[mi][ni][r];
        if constexpr (EPI == 1) v += bscale * bias[col];
        if constexpr (EPI == 2) v = res[(size_t)row * 256 + col] + ada[(row / 384) * 1536 + gate_off + col] * v;
        if constexpr (EPI == 3) v = (res[(size_t)row * 256 + col] + ada[(row / 384) * 1536 + gate_off + col] * v) * mask[row];
        if constexpr (EPI == 4) C[(size_t)col * ldc + row] = v;
        else C[(size_t)row * ldc + col] = v;
      }
}

// ---------------- edge message kernel: block per (b,i).
// S[b,i,h] = sum_j silu( em_ij*(P[b,i,h] + Qt[h, b*384+j] + dist[b,i,j,:]@W1d[h,:]) + b1[h] )
__global__ __launch_bounds__(256)
void k_edge(const float* __restrict__ dist, const float* __restrict__ emask,
            const float* __restrict__ Wfe1, const float* __restrict__ bfe1,
            const float* __restrict__ P, const float* __restrict__ Qt,
            float* __restrict__ S) {
  const int blk = blockIdx.x;
  const int b = blk / 384, i = blk - b * 384;
  const int t = threadIdx.x, lane = t & 63, w = t >> 6;
  const int g = lane >> 4, c = lane & 15;
  __shared__ __align__(16) unsigned short Al[32 * 128];  // 8KB, oct ^= (row&7) swizzle

  // W1d fragments (B operand), held in registers: wave w covers h in [w*64, w*64+64)
  bf16x8 Bf[4][4];
#pragma unroll
  for (int ht = 0; ht < 4; ++ht) {
    const int h = w * 64 + ht * 16 + c;
    const float* wp = Wfe1 + (size_t)h * 640 + 512 + g * 8;
#pragma unroll
    for (int ks = 0; ks < 4; ++ks)
      Bf[ht][ks] = asbf(pk8(ldv4(wp + ks * 32), ldv4(wp + ks * 32 + 4)));
  }
  float Pl[4], bl[4];
#pragma unroll
  for (int ht = 0; ht < 4; ++ht) {
    int h = w * 64 + ht * 16 + c;
    Pl[ht] = P[(size_t)(b * 384 + i) * 256 + h];
    bl[ht] = bfe1[h];
  }
  float Ss[4] = {0.f, 0.f, 0.f, 0.f};

  const int srow = t >> 3;        // 0..31 (j within chunk)
  const int so = (t & 7) * 2;     // octet 0..14 even
  unsigned short* awr0 = Al + srow * 128 + ((so ^ (srow & 7))) * 8;
  unsigned short* awr1 = Al + srow * 128 + (((so + 1) ^ (srow & 7))) * 8;
  const float* dbase = dist + (size_t)(b * 384 + i) * (384 * 128);
  const float* embase = emask + (size_t)(b * 384 + i) * 384;

  fv4 d0, d1, d2, d3;
  {
    const float* dg = dbase + srow * 128 + so * 8;
    d0 = ldv4(dg); d1 = ldv4(dg + 4); d2 = ldv4(dg + 8); d3 = ldv4(dg + 12);
  }
  for (int j0 = 0; j0 < 384; j0 += 32) {
    __syncthreads();
    *reinterpret_cast<u16x8*>(awr0) = pk8(d0, d1);
    *reinterpret_cast<u16x8*>(awr1) = pk8(d2, d3);
    __syncthreads();
    if (j0 + 32 < 384) {  // prefetch next dist chunk
      const float* dg = dbase + (size_t)(j0 + 32 + srow) * 128 + so * 8;
      d0 = ldv4(dg); d1 = ldv4(dg + 4); d2 = ldv4(dg + 8); d3 = ldv4(dg + 12);
    }
    fv4 emv[2];
    fv4 qv[4][2];
#pragma unroll
    for (int mt = 0; mt < 2; ++mt)
      emv[mt] = ldv4(embase + j0 + mt * 16 + g * 4);
#pragma unroll
    for (int ht = 0; ht < 4; ++ht) {
      int h = w * 64 + ht * 16 + c;
#pragma unroll
      for (int mt = 0; mt < 2; ++mt)
        qv[ht][mt] = ldv4(Qt + (size_t)h * 768 + b * 384 + j0 + mt * 16 + g * 4);
    }
    fv4 acc[2][4] = {};
#pragma unroll
    for (int mt = 0; mt < 2; ++mt) {
#pragma unroll
      for (int ks = 0; ks < 4; ++ks) {
        int j = mt * 16 + c;
        int oct = (ks * 4 + g) ^ (j & 7);
        bf16x8 af = asbf(*reinterpret_cast<const u16x8*>(Al + j * 128 + oct * 8));
#pragma unroll
        for (int ht = 0; ht < 4; ++ht)
          acc[mt][ht] = MFMA16(af, Bf[ht][ks], acc[mt][ht]);
      }
    }
#pragma unroll
    for (int mt = 0; mt < 2; ++mt)
#pragma unroll
      for (int ht = 0; ht < 4; ++ht)
#pragma unroll
        for (int r = 0; r < 4; ++r) {
          float pre = emv[mt][r] * (Pl[ht] + qv[ht][mt][r] + acc[mt][ht][r]) + bl[ht];
          Ss[ht] += siluf(pre);
        }
  }
#pragma unroll
  for (int ht = 0; ht < 4; ++ht) {
    float s = Ss[ht];
    s += __shfl_xor(s, 16);
    s += __shfl_xor(s, 32);
    if (g == 0) S[(size_t)(b * 384 + i) * 256 + w * 64 + ht * 16 + c] = s;
  }
}

// ---------------- LN(Q*mask), LN(K*mask) over full H=256
__global__ __launch_bounds__(256)
void k_lnqk(const float* __restrict__ qkv, const float* __restrict__ mask,
            float* __restrict__ Qn, float* __restrict__ Kn) {
  const int row = blockIdx.x, t = threadIdx.x;
  const float m = mask[row];
  const float q = qkv[(size_t)row * 768 + t] * m;
  const float k = qkv[(size_t)row * 768 + 256 + t] * m;
  float sq = q, sqq = q * q, sk = k, skk = k * k;
#pragma unroll
  for (int o = 1; o < 64; o <<= 1) {
    sq += __shfl_xor(sq, o); sqq += __shfl_xor(sqq, o);
    sk += __shfl_xor(sk, o); skk += __shfl_xor(skk, o);
  }
  __shared__ float red[16];
  const int wid = t >> 6;
  if ((t & 63) == 0) { red[wid] = sq; red[4 + wid] = sqq; red[8 + wid] = sk; red[12 + wid] = skk; }
  __syncthreads();
  sq = red[0] + red[1] + red[2] + red[3];
  sqq = red[4] + red[5] + red[6] + red[7];
  sk = red[8] + red[9] + red[10] + red[11];
  skk = red[12] + red[13] + red[14] + red[15];
  const float mq = sq * (1.f / 256.f), vq = sqq * (1.f / 256.f) - mq * mq;
  const float mk = sk * (1.f / 256.f), vk = skk * (1.f / 256.f) - mk * mk;
  Qn[(size_t)row * 256 + t] = (q - mq) * rsqrtf(vq + 1e-6f);
  Kn[(size_t)row * 256 + t] = (k - mk) * rsqrtf(vk + 1e-6f);
}

// ---------------- attention: block = (qgroup of 4 rows) x (b,h); wave per q-row
__global__ __launch_bounds__(256)
void k_attn(const float* __restrict__ Qn, const float* __restrict__ Kn,
            const float* __restrict__ qkv, const float* __restrict__ mask,
            float* __restrict__ ao) {
  const int bh = blockIdx.y, b = bh >> 3, h = bh & 7;
  const int qg = blockIdx.x;
  const int t = threadIdx.x, lane = t & 63, w = t >> 6;
  __shared__ __align__(8) unsigned short Kl[384 * 36];
  __shared__ __align__(8) unsigned short Vl[384 * 36];
  __shared__ float ql[4][32];
  __shared__ float pl[4][384];
  {
    const int rr = t >> 3, d0 = (t & 7) * 4;
#pragma unroll
    for (int s = 0; s < 12; ++s) {
      int row = s * 32 + rr;
      fv4 kv = ldv4(Kn + (size_t)(b * 384 + row) * 256 + h * 32 + d0);
      fv4 vv = ldv4(qkv + (size_t)(b * 384 + row) * 768 + 512 + h * 32 + d0);
      u16x4 ku, vu;
      ku[0] = f2bf(kv[0]); ku[1] = f2bf(kv[1]); ku[2] = f2bf(kv[2]); ku[3] = f2bf(kv[3]);
      vu[0] = f2bf(vv[0]); vu[1] = f2bf(vv[1]); vu[2] = f2bf(vv[2]); vu[3] = f2bf(vv[3]);
      *reinterpret_cast<u16x4*>(Kl + row * 36 + d0) = ku;
      *reinterpret_cast<u16x4*>(Vl + row * 36 + d0) = vu;
    }
  }
  if (t < 128) {
    int qq = t >> 5, d = t & 31;
    ql[qq][d] = Qn[(size_t)(b * 384 + qg * 4 + qq) * 256 + h * 32 + d];
  }
  __syncthreads();
  // scores: 6 per lane (k = mki*64 + lane)
  float sc[6];
  const float rs = 0.1767766952966369f;  // 1/sqrt(32)
#pragma unroll
  for (int mki = 0; mki < 6; ++mki) {
    int k = mki * 64 + lane;
    float s = 0.f;
#pragma unroll
    for (int d = 0; d < 32; d += 2) {
      unsigned int uu = *reinterpret_cast<const unsigned int*>(Kl + k * 36 + d);
      float k0 = __builtin_bit_cast(float, uu << 16);
      float k1 = __builtin_bit_cast(float, uu & 0xffff0000u);
      s += ql[w][d] * k0 + ql[w][d + 1] * k1;
    }
    sc[mki] = s * rs + (mask[b * 384 + k] > 0.f ? 0.f : -1e9f);
  }
  float mx = sc[0];
#pragma unroll
  for (int mki = 1; mki < 6; ++mki) mx = fmaxf(mx, sc[mki]);
#pragma unroll
  for (int o = 1; o < 64; o <<= 1) mx = fmaxf(mx, __shfl_xor(mx, o));
  float sum = 0.f;
#pragma unroll
  for (int mki = 0; mki < 6; ++mki) { float p = __expf(sc[mki] - mx); sc[mki] = p; sum += p; }
#pragma unroll
  for (int o = 1; o < 64; o <<= 1) sum += __shfl_xor(sum, o);
  const float inv = 1.f / sum;
#pragma unroll
  for (int mki = 0; mki < 6; ++mki) pl[w][mki * 64 + lane] = sc[mki] * inv;
  __syncthreads();
  // PV: lanes 0..31 take k<192, lanes 32..63 take k>=192; d = lane&31
  const int d = lane & 31, half = lane >> 5;
  float outv = 0.f;
  for (int k = half * 192; k < half * 192 + 192; ++k) {
    float p = pl[w][k];
    outv += p * __builtin_bit_cast(float, ((unsigned int)Vl[k * 36 + d]) << 16);
  }
  outv += __shfl_xor(outv, 32);
  if (lane < 32) {
    int q = qg * 4 + w;
    ao[(size_t)(b * 384 + q) * 256 + h * 32 + d] = outv;
  }
}

// ---------------- SwiGLU elementwise: g = silu(h_a) * h_b
__global__ __launch_bounds__(256)
void k_glu(const float* __restrict__ h12, float* __restrict__ gout) {
  int idx = blockIdx.x * 256 + threadIdx.x;
  if (idx < 768 * 1024) {
    int r = idx >> 10, cc = idx & 1023;
    float a = h12[(size_t)r * 2048 + cc];
    float bb = h12[(size_t)r * 2048 + 1024 + cc];
    gout[idx] = siluf(a) * bb;
  }
}

extern "C" void kernel_launch(void* const* d_in, const int* in_sizes, int n_in,
                              void* d_out, int out_size, void* d_ws, size_t ws_size,
                              hipStream_t stream) {
  (void)in_sizes; (void)n_in; (void)out_size; (void)ws_size;
  const float* mask   = (const float*)d_in[0];
  const float* x      = (const float*)d_in[1];
  const float* temb   = (const float*)d_in[2];
  const float* dist   = (const float*)d_in[3];
  const float* emask  = (const float*)d_in[4];
  const float* W_ada  = (const float*)d_in[5];
  const float* b_ada  = (const float*)d_in[6];
  const float* W_fe1  = (const float*)d_in[7];
  const float* b_fe1  = (const float*)d_in[8];
  const float* W_fe2  = (const float*)d_in[9];
  const float* b_fe2  = (const float*)d_in[10];
  const float* W_qkv  = (const float*)d_in[11];
  const float* W_out  = (const float*)d_in[12];
  const float* W_ffn1 = (const float*)d_in[13];
  const float* W_ffn2 = (const float*)d_in[14];
  float* out = (float*)d_out;
  float* ws = (float*)d_ws;

  // workspace layout (floats); h12/gbuf alias buffers that are dead by the time they run
  float* ada   = ws;              // 3072
  float* xattn = ws + 4096;       // 196608
  float* xm    = ws + 200704;     // 196608
  float* xn    = ws + 397312;     // 196608
  float* P     = ws + 593920;     // 196608
  float* Qt    = ws + 790528;     // 196608 (transposed: [h][b*384+j])
  float* S     = ws + 987136;     // 196608
  float* xmsg  = ws + 1183744;    // 196608
  float* qkvb  = ws + 1380352;    // 589824
  float* Qn    = ws + 1970176;    // 196608
  float* Kn    = ws + 2166784;    // 196608
  float* aob   = ws + 2363392;    // 196608
  float* h12   = ws + 397312;     // 1572864, aliases xn..qkvb (dead)
  float* gbuf  = ws + 1970176;    // 786432, aliases Qn/Kn/aob (dead)

  k_ada<<<12, 256, 0, stream>>>(temb, W_ada, b_ada, ada);
  k_xnorm<<<768, 256, 0, stream>>>(x, mask, ada, 0, 256, xn);
  // P = xn @ W_fe1[:, 0:256]^T ; Qt = (xn @ W_fe1[:, 256:512]^T)^T
  k_gemm<0><<<dim3(4, 12), 256, 0, stream>>>(xn, 256, W_fe1, 640, 0, 256, P, 256,
                                             nullptr, 0.f, nullptr, nullptr, 0, nullptr);
  k_gemm<4><<<dim3(4, 12), 256, 0, stream>>>(xn, 256, W_fe1, 640, 256, 256, Qt, 768,
                                             nullptr, 0.f, nullptr, nullptr, 0, nullptr);
  k_edge<<<768, 256, 0, stream>>>(dist, emask, W_fe1, b_fe1, P, Qt, S);
  // x_msg = S @ W_fe2^T + 384*b_fe2
  k_gemm<1><<<dim3(4, 12), 256, 0, stream>>>(S, 256, W_fe2, 256, 0, 256, xmsg, 256,
                                             b_fe2, 384.f, nullptr, nullptr, 0, nullptr);
  k_gemm<0><<<dim3(12, 12), 256, 0, stream>>>(xmsg, 256, W_qkv, 256, 0, 256, qkvb, 768,
                                              nullptr, 0.f, nullptr, nullptr, 0, nullptr);
  k_lnqk<<<768, 256, 0, stream>>>(qkvb, mask, Qn, Kn);
  k_attn<<<dim3(96, 16), 256, 0, stream>>>(Qn, Kn, qkvb, mask, aob);
  // x_attn = x + gate_msa * (ao @ W_out^T)
  k_gemm<2><<<dim3(4, 12), 256, 0, stream>>>(aob, 256, W_out, 256, 0, 256, xattn, 256,
                                             nullptr, 0.f, x, ada, 512, nullptr);
  k_xnorm<<<768, 256, 0, stream>>>(xattn, mask, ada, 768, 1024, xm);
  k_gemm<0><<<dim3(32, 12), 256, 0, stream>>>(xm, 256, W_ffn1, 256, 0, 256, h12, 2048,
                                              nullptr, 0.f, nullptr, nullptr, 0, nullptr);
  k_glu<<<3072, 256, 0, stream>>>(h12, gbuf);
  // out = (x_attn + gate_mlp * (g @ W_ffn2^T)) * mask
  k_gemm<3><<<dim3(4, 12), 256, 0, stream>>>(gbuf, 1024, W_ffn2, 1024, 0, 1024, out, 256,
                                             nullptr, 0.f, xattn, ada, 1280, mask);
}